// Round 1
// baseline (344.041 us; speedup 1.0000x reference)
//
#include <hip/hip_runtime.h>
#include <math.h>

#define NN 8192
#define DD 64
#define SS 4096
#define CNCAP 64          // common-neighbor list cap (expected ~0.13 per sample)
#define SMB 1024          // number of blocks that handle the L_smooth slices
#define SMBASE (SS - SMB) // blocks [SMBASE, SS) each cover one 256-float2 chunk

// Butterfly reduce within a 64-lane wave: result replicated on all lanes.
__device__ __forceinline__ float wred(float v) {
    #pragma unroll
    for (int o = 1; o < 64; o <<= 1) v += __shfl_xor(v, o);
    return v;
}

// ws layout: [0,16) counters, [16, 16+4*SS) order[],
// float2 part[SS] at 16400, float sm_part[SMB] at 49168.

// Order samples heavy-first (cond==1 first). Wave-aggregated atomics.
__global__ void __launch_bounds__(256) partition_kernel(
        const int* __restrict__ cond, int* __restrict__ counters,
        int* __restrict__ order) {
    int t = blockIdx.x * 256 + threadIdx.x;
    if (t < SS) {
        int c = cond[t];
        int p;
        if (c == 1) p = atomicAdd(&counters[0], 1);
        else        p = SS - 1 - atomicAdd(&counters[1], 1);
        order[p] = t;
    }
}

// 256 threads (4 waves) per block.
//  - blocks [0, H): one heavy (cond==1) sample each; 4 waves co-scan rows i,j.
//  - blocks [H, ...): light samples, 4 per block (one per wave).
//  - blocks [SMBASE, SS): additionally cover one L_smooth chunk each.
__global__ void __launch_bounds__(256) fused_sample_kernel(
        const float* __restrict__ E, const float* __restrict__ Eprev,
        const float* __restrict__ theta, const float* __restrict__ adj,
        const int* __restrict__ j_idx, const int* __restrict__ k_idx,
        const int* __restrict__ nj_idx, const int* __restrict__ i_idx,
        const int* __restrict__ cond, const int* __restrict__ counters,
        const int* __restrict__ order,
        float2* __restrict__ part, float* __restrict__ sm_part) {
    const int b    = blockIdx.x;
    const int tid  = threadIdx.x;
    const int lane = tid & 63;
    const int wv   = tid >> 6;
    const int H    = counters[0];   // number of cond==1 samples

    // ---- L_smooth: last SMB blocks each cover 256 float2 of (E - Eprev) ----
    if (b >= SMBASE) {
        const float2* a2 = (const float2*)E;
        const float2* b2 = (const float2*)Eprev;
        int idx = (b - SMBASE) * 256 + tid;
        float2 x = a2[idx], y = b2[idx];
        float dx = x.x - y.x, dy = x.y - y.y;
        float sm = wred(dx * dx + dy * dy);
        __shared__ float smw[4];
        if (lane == 0) smw[wv] = sm;
        __syncthreads();
        if (tid == 0) sm_part[b - SMBASE] = smw[0] + smw[1] + smw[2] + smw[3];
    }

    if (b < H) {
        // ================= heavy sample: cond == 1 =================
        int s = order[b];
        int j = j_idx[s], k = k_idx[s], i = i_idx[s];

        // all 4 waves need ui, uj for Phase C dot products (cached reads)
        float ui = E[(size_t)i * DD + lane];
        float uj = E[(size_t)j * DD + lane];

        __shared__ int   cn_idx[CNCAP];
        __shared__ float cn_a[CNCAP];
        __shared__ float cn_b[CNCAP];
        __shared__ int   cn_cnt;
        __shared__ float wprod[4];
        if (tid == 0) cn_cnt = 0;
        __syncthreads();

        // Phase A: wave wv dual-streams quarter wv of rows i and j (8 KB each),
        // detects common neighbors branch-free, pushes rare hits via LDS atomic.
        const float4* ri = (const float4*)(adj + (size_t)i * NN) + wv * 512;
        const float4* rj = (const float4*)(adj + (size_t)j * NN) + wv * 512;
        float4 Ar[8], Br[8];
        #pragma unroll
        for (int it = 0; it < 8; ++it) Ar[it] = ri[it * 64 + lane];
        #pragma unroll
        for (int it = 0; it < 8; ++it) Br[it] = rj[it * 64 + lane];
        #pragma unroll
        for (int it = 0; it < 8; ++it) {
            float4 a = Ar[it], bb = Br[it];
            float m0 = fminf(a.x, bb.x), m1 = fminf(a.y, bb.y);
            float m2 = fminf(a.z, bb.z), m3 = fminf(a.w, bb.w);
            if (fmaxf(fmaxf(m0, m1), fmaxf(m2, m3)) > 0.f) {   // ~0.13 hits/block
                int cb = (wv * 512 + it * 64 + lane) * 4;
                if (m0 > 0.f) { int p = atomicAdd(&cn_cnt, 1); if (p < CNCAP) { cn_idx[p] = cb + 0; cn_a[p] = a.x; cn_b[p] = bb.x; } }
                if (m1 > 0.f) { int p = atomicAdd(&cn_cnt, 1); if (p < CNCAP) { cn_idx[p] = cb + 1; cn_a[p] = a.y; cn_b[p] = bb.y; } }
                if (m2 > 0.f) { int p = atomicAdd(&cn_cnt, 1); if (p < CNCAP) { cn_idx[p] = cb + 2; cn_a[p] = a.z; cn_b[p] = bb.z; } }
                if (m3 > 0.f) { int p = atomicAdd(&cn_cnt, 1); if (p < CNCAP) { cn_idx[p] = cb + 3; cn_a[p] = a.w; cn_b[p] = bb.w; } }
            }
        }
        __syncthreads();
        int cnt = cn_cnt; if (cnt > CNCAP) cnt = CNCAP;

        // Phase C: wave wv handles entries wv, wv+4, ... (cooperative D=64 dots)
        float pprod = 1.f;
        for (int p = wv; p < cnt; p += 4) {
            int l = cn_idx[p];
            float ai = cn_a[p], bj = cn_b[p];
            float th = theta[(size_t)l * DD + lane];
            float ul = E[(size_t)l * DD + lane];
            float r1 = wred(th * (ul - ui));   // diag[l] - theta_l.u_i
            float r2 = wred(th * (ul - uj));   // diag[l] - theta_l.u_j
            float dl = ai * r1 + bj * r2;
            float P = (dl < -100.f) ? 0.f : 1.f / (1.f + __expf(-dl));
            pprod *= (1.f - P);
        }
        if (lane == 0) wprod[wv] = pprod;
        __syncthreads();

        // wave 0: per-sample scalar terms + emit
        if (wv == 0) {
            int nj = nj_idx[s];
            float uk  = E[(size_t)k  * DD + lane];
            float un  = E[(size_t)nj * DD + lane];
            float thk = theta[(size_t)k * DD + lane];
            float aik = adj[(size_t)i * NN + k];
            float ajk = adj[(size_t)j * NN + k];
            float dp = uj - uk, dn = un - uk;
            float pos = wred(dp * dp);
            float neg = wred(dn * dn);
            float tik = wred(thk * ui);
            float tjk = wred(thk * uj);
            float dgk = wred(thk * uk);
            if (lane == 0) {
                float lsh = fmaxf(pos - neg + 1.0f, 0.f);
                float dot_k = aik * (dgk - tik) + ajk * (dgk - tjk);
                float x = -dot_k;
                float logp = fmaxf(x, 0.f) + log1pf(expf(-fabsf(x)));
                float prod = wprod[0] * wprod[1] * wprod[2] * wprod[3];
                float C1 = 1.f - prod;
                float C0 = (dot_k < -100.f) ? 0.f : 1.f / (1.f + expf(-dot_k));
                float ltr = logp + (1.f - C0 / (C1 + 1e-6f));
                part[s] = make_float2(lsh, ltr);
            }
        }
    } else {
        // ================= light samples: 4 per block, one per wave =================
        int sidx = H + (b - H) * 4 + wv;
        if (sidx < SS) {
            int s = order[sidx];
            int j = j_idx[s], k = k_idx[s], nj = nj_idx[s], i = i_idx[s], c = cond[s];
            float ui  = E[(size_t)i  * DD + lane];
            float uj  = E[(size_t)j  * DD + lane];
            float uk  = E[(size_t)k  * DD + lane];
            float un  = E[(size_t)nj * DD + lane];
            float thk = theta[(size_t)k * DD + lane];
            float aik = adj[(size_t)i * NN + k];
            float ajk = adj[(size_t)j * NN + k];
            float dp = uj - uk, dn = un - uk;
            float pos = wred(dp * dp);
            float neg = wred(dn * dn);
            float tik = wred(thk * ui);
            float tjk = wred(thk * uj);
            float dgk = wred(thk * uk);
            if (lane == 0) {
                float lsh = fmaxf(pos - neg + 1.0f, 0.f);
                float dot_k = aik * (dgk - tik) + ajk * (dgk - tjk);
                float x = -dot_k;
                float logp = fmaxf(x, 0.f) + log1pf(expf(-fabsf(x)));
                float ltr = (c == -1) ? 0.f : (logp + dot_k);
                part[s] = make_float2(lsh, ltr);
            }
        }
    }
}

// Single block: reduce partials in double, emit the scalar loss.
__global__ void __launch_bounds__(256) final_reduce_kernel(
        const float2* __restrict__ part, const float* __restrict__ sm_part,
        float* __restrict__ out) {
    double lsh = 0.0, ltr = 0.0, sm = 0.0;
    for (int t = threadIdx.x; t < SS; t += 256) {
        float2 p = part[t];
        lsh += (double)p.x;
        ltr += (double)p.y;
    }
    for (int t = threadIdx.x; t < SMB; t += 256) sm += (double)sm_part[t];
    #pragma unroll
    for (int o = 32; o; o >>= 1) {
        lsh += __shfl_down(lsh, o);
        ltr += __shfl_down(ltr, o);
        sm  += __shfl_down(sm, o);
    }
    __shared__ double sh[3][4];
    int lane = threadIdx.x & 63, wv = threadIdx.x >> 6;
    if (lane == 0) { sh[0][wv] = lsh; sh[1][wv] = ltr; sh[2][wv] = sm; }
    __syncthreads();
    if (threadIdx.x == 0) {
        double L = (sh[0][0] + sh[0][1] + sh[0][2] + sh[0][3])
                 + 0.1 * (sh[1][0] + sh[1][1] + sh[1][2] + sh[1][3])
                 + 0.1 * (double)SS * (sh[2][0] + sh[2][1] + sh[2][2] + sh[2][3]);
        out[0] = (float)L;
    }
}

extern "C" void kernel_launch(void* const* d_in, const int* in_sizes, int n_in,
                              void* d_out, int out_size, void* d_ws, size_t ws_size,
                              hipStream_t stream) {
    const float* emb_t    = (const float*)d_in[0];
    const float* emb_prev = (const float*)d_in[1];
    const float* theta    = (const float*)d_in[2];
    const float* adj      = (const float*)d_in[3];
    const int*   j_idx    = (const int*)d_in[4];
    const int*   k_idx    = (const int*)d_in[5];
    const int*   nj_idx   = (const int*)d_in[6];
    const int*   i_idx    = (const int*)d_in[7];
    const int*   cond     = (const int*)d_in[8];
    float* out = (float*)d_out;

    int*    counters = (int*)d_ws;                              // 2 ints (+pad)
    int*    order    = (int*)((char*)d_ws + 16);                // SS ints
    float2* part     = (float2*)((char*)d_ws + 16 + 4 * SS);    // 8-aligned
    float*  sm_part  = (float*)((char*)d_ws + 16 + 4 * SS + 8 * SS);

    hipMemsetAsync(d_ws, 0, 16, stream);
    partition_kernel<<<SS / 256, 256, 0, stream>>>(cond, counters, order);
    fused_sample_kernel<<<SS, 256, 0, stream>>>(
        emb_t, emb_prev, theta, adj, j_idx, k_idx, nj_idx, i_idx, cond,
        counters, order, part, sm_part);
    final_reduce_kernel<<<1, 256, 0, stream>>>(part, sm_part, out);
}

// Round 2
// 339.652 us; speedup vs baseline: 1.0129x; 1.0129x over previous
//
#include <hip/hip_runtime.h>
#include <math.h>

#define NN 8192
#define DD 64
#define SS 4096
#define CNCAP 64          // common-neighbor list cap (expected ~0.13 per sample)
#define SMB 1024          // number of blocks that also handle an L_smooth slice
#define SMBASE (SS - SMB) // blocks [SMBASE, SS) each cover one 256-float2 chunk

// Butterfly reduce within a 64-lane wave: result replicated on all lanes.
__device__ __forceinline__ float wred(float v) {
    #pragma unroll
    for (int o = 1; o < 64; o <<= 1) v += __shfl_xor(v, o);
    return v;
}

// ws layout: float2 part[SS] at 0 (32 KB), float sm_part[SMB] at 32768 (4 KB).
// Every slot is unconditionally written each launch -> no zeroing needed,
// no dependence on workspace contents (re-poison safe).

// 256 threads (4 waves) per block. Block b handles sample s=b.
//  - cond==1 blocks: 4 waves dual-stream rows i,j of adj for common neighbors.
//  - light blocks: wave 0 computes the closed-form terms, rest idle (short).
//  - blocks [SMBASE, SS): additionally reduce one 2 KB L_smooth chunk.
__global__ void __launch_bounds__(256) fused_all_kernel(
        const float* __restrict__ E, const float* __restrict__ Eprev,
        const float* __restrict__ theta, const float* __restrict__ adj,
        const int* __restrict__ j_idx, const int* __restrict__ k_idx,
        const int* __restrict__ nj_idx, const int* __restrict__ i_idx,
        const int* __restrict__ cond,
        float2* __restrict__ part, float* __restrict__ sm_part) {
    const int b    = blockIdx.x;
    const int tid  = threadIdx.x;
    const int lane = tid & 63;
    const int wv   = tid >> 6;

    __shared__ float smw[4];
    __shared__ int   cn_idx[CNCAP];
    __shared__ float cn_a[CNCAP];
    __shared__ float cn_b[CNCAP];
    __shared__ int   cn_cnt;
    __shared__ float wprod[4];

    // ---- L_smooth: last SMB blocks each reduce 256 float2 of (E - Eprev) ----
    if (b >= SMBASE) {
        const float2* a2 = (const float2*)E;
        const float2* b2 = (const float2*)Eprev;
        int idx = (b - SMBASE) * 256 + tid;
        float2 x = a2[idx], y = b2[idx];
        float dx = x.x - y.x, dy = x.y - y.y;
        float sm = wred(dx * dx + dy * dy);
        if (lane == 0) smw[wv] = sm;
        __syncthreads();
        if (tid == 0) sm_part[b - SMBASE] = smw[0] + smw[1] + smw[2] + smw[3];
    }

    const int s = b;
    const int c = cond[s];
    const int j = j_idx[s], k = k_idx[s], i = i_idx[s];

    if (c == 1) {
        // ================= heavy sample =================
        // all 4 waves need ui, uj for Phase C dot products (cached reads)
        float ui = E[(size_t)i * DD + lane];
        float uj = E[(size_t)j * DD + lane];

        if (tid == 0) cn_cnt = 0;
        __syncthreads();

        // Phase A: wave wv dual-streams quarter wv of rows i and j (8 KB each),
        // detects common neighbors branch-free, pushes rare hits via LDS atomic.
        const float4* ri = (const float4*)(adj + (size_t)i * NN) + wv * 512;
        const float4* rj = (const float4*)(adj + (size_t)j * NN) + wv * 512;
        float4 Ar[8], Br[8];
        #pragma unroll
        for (int it = 0; it < 8; ++it) Ar[it] = ri[it * 64 + lane];
        #pragma unroll
        for (int it = 0; it < 8; ++it) Br[it] = rj[it * 64 + lane];
        #pragma unroll
        for (int it = 0; it < 8; ++it) {
            float4 a = Ar[it], bb = Br[it];
            float m0 = fminf(a.x, bb.x), m1 = fminf(a.y, bb.y);
            float m2 = fminf(a.z, bb.z), m3 = fminf(a.w, bb.w);
            if (fmaxf(fmaxf(m0, m1), fmaxf(m2, m3)) > 0.f) {   // ~0.13 hits/block
                int cb = (wv * 512 + it * 64 + lane) * 4;
                if (m0 > 0.f) { int p = atomicAdd(&cn_cnt, 1); if (p < CNCAP) { cn_idx[p] = cb + 0; cn_a[p] = a.x; cn_b[p] = bb.x; } }
                if (m1 > 0.f) { int p = atomicAdd(&cn_cnt, 1); if (p < CNCAP) { cn_idx[p] = cb + 1; cn_a[p] = a.y; cn_b[p] = bb.y; } }
                if (m2 > 0.f) { int p = atomicAdd(&cn_cnt, 1); if (p < CNCAP) { cn_idx[p] = cb + 2; cn_a[p] = a.z; cn_b[p] = bb.z; } }
                if (m3 > 0.f) { int p = atomicAdd(&cn_cnt, 1); if (p < CNCAP) { cn_idx[p] = cb + 3; cn_a[p] = a.w; cn_b[p] = bb.w; } }
            }
        }
        __syncthreads();
        int cnt = cn_cnt; if (cnt > CNCAP) cnt = CNCAP;

        // Phase C: wave wv handles entries wv, wv+4, ... (cooperative D=64 dots)
        float pprod = 1.f;
        for (int p = wv; p < cnt; p += 4) {
            int l = cn_idx[p];
            float ai = cn_a[p], bj = cn_b[p];
            float th = theta[(size_t)l * DD + lane];
            float ul = E[(size_t)l * DD + lane];
            float r1 = wred(th * (ul - ui));   // diag[l] - theta_l.u_i
            float r2 = wred(th * (ul - uj));   // diag[l] - theta_l.u_j
            float dl = ai * r1 + bj * r2;
            float P = (dl < -100.f) ? 0.f : 1.f / (1.f + __expf(-dl));
            pprod *= (1.f - P);
        }
        if (lane == 0) wprod[wv] = pprod;
        __syncthreads();

        // wave 0: per-sample scalar terms + emit
        if (wv == 0) {
            int nj = nj_idx[s];
            float uk  = E[(size_t)k  * DD + lane];
            float un  = E[(size_t)nj * DD + lane];
            float thk = theta[(size_t)k * DD + lane];
            float aik = adj[(size_t)i * NN + k];
            float ajk = adj[(size_t)j * NN + k];
            float dp = uj - uk, dn = un - uk;
            float pos = wred(dp * dp);
            float neg = wred(dn * dn);
            float tik = wred(thk * ui);
            float tjk = wred(thk * uj);
            float dgk = wred(thk * uk);
            if (lane == 0) {
                float lsh = fmaxf(pos - neg + 1.0f, 0.f);
                float dot_k = aik * (dgk - tik) + ajk * (dgk - tjk);
                float x = -dot_k;
                float logp = fmaxf(x, 0.f) + log1pf(expf(-fabsf(x)));
                float prod = wprod[0] * wprod[1] * wprod[2] * wprod[3];
                float C1 = 1.f - prod;
                float C0 = (dot_k < -100.f) ? 0.f : 1.f / (1.f + expf(-dot_k));
                float ltr = logp + (1.f - C0 / (C1 + 1e-6f));
                part[s] = make_float2(lsh, ltr);
            }
        }
    } else {
        // ================= light sample: wave 0 only =================
        if (wv == 0) {
            int nj = nj_idx[s];
            float ui  = E[(size_t)i  * DD + lane];
            float uj  = E[(size_t)j  * DD + lane];
            float uk  = E[(size_t)k  * DD + lane];
            float un  = E[(size_t)nj * DD + lane];
            float thk = theta[(size_t)k * DD + lane];
            float aik = adj[(size_t)i * NN + k];
            float ajk = adj[(size_t)j * NN + k];
            float dp = uj - uk, dn = un - uk;
            float pos = wred(dp * dp);
            float neg = wred(dn * dn);
            float tik = wred(thk * ui);
            float tjk = wred(thk * uj);
            float dgk = wred(thk * uk);
            if (lane == 0) {
                float lsh = fmaxf(pos - neg + 1.0f, 0.f);
                float dot_k = aik * (dgk - tik) + ajk * (dgk - tjk);
                float x = -dot_k;
                float logp = fmaxf(x, 0.f) + log1pf(expf(-fabsf(x)));
                float ltr = (c == -1) ? 0.f : (logp + dot_k);
                part[s] = make_float2(lsh, ltr);
            }
        }
    }
}

// Single block: reduce partials in double, emit the scalar loss.
__global__ void __launch_bounds__(256) final_reduce_kernel(
        const float2* __restrict__ part, const float* __restrict__ sm_part,
        float* __restrict__ out) {
    double lsh = 0.0, ltr = 0.0, sm = 0.0;
    for (int t = threadIdx.x; t < SS; t += 256) {
        float2 p = part[t];
        lsh += (double)p.x;
        ltr += (double)p.y;
    }
    for (int t = threadIdx.x; t < SMB; t += 256) sm += (double)sm_part[t];
    #pragma unroll
    for (int o = 32; o; o >>= 1) {
        lsh += __shfl_down(lsh, o);
        ltr += __shfl_down(ltr, o);
        sm  += __shfl_down(sm, o);
    }
    __shared__ double sh[3][4];
    int lane = threadIdx.x & 63, wv = threadIdx.x >> 6;
    if (lane == 0) { sh[0][wv] = lsh; sh[1][wv] = ltr; sh[2][wv] = sm; }
    __syncthreads();
    if (threadIdx.x == 0) {
        double L = (sh[0][0] + sh[0][1] + sh[0][2] + sh[0][3])
                 + 0.1 * (sh[1][0] + sh[1][1] + sh[1][2] + sh[1][3])
                 + 0.1 * (double)SS * (sh[2][0] + sh[2][1] + sh[2][2] + sh[2][3]);
        out[0] = (float)L;
    }
}

extern "C" void kernel_launch(void* const* d_in, const int* in_sizes, int n_in,
                              void* d_out, int out_size, void* d_ws, size_t ws_size,
                              hipStream_t stream) {
    const float* emb_t    = (const float*)d_in[0];
    const float* emb_prev = (const float*)d_in[1];
    const float* theta    = (const float*)d_in[2];
    const float* adj      = (const float*)d_in[3];
    const int*   j_idx    = (const int*)d_in[4];
    const int*   k_idx    = (const int*)d_in[5];
    const int*   nj_idx   = (const int*)d_in[6];
    const int*   i_idx    = (const int*)d_in[7];
    const int*   cond     = (const int*)d_in[8];
    float* out = (float*)d_out;

    float2* part    = (float2*)d_ws;                     // SS float2, all written
    float*  sm_part = (float*)((char*)d_ws + 8 * SS);    // SMB floats, all written

    fused_all_kernel<<<SS, 256, 0, stream>>>(
        emb_t, emb_prev, theta, adj, j_idx, k_idx, nj_idx, i_idx, cond,
        part, sm_part);
    final_reduce_kernel<<<1, 256, 0, stream>>>(part, sm_part, out);
}